// Round 6
// baseline (469.580 us; speedup 1.0000x reference)
//
#include <hip/hip_runtime.h>

// PrimaryCaps implicit GEMM, round 6:
//   r5's swapped MFMA (register-local squash, 1 shfl/group) + (256,3) occupancy,
//   with the store fixed: r5's column-major float4 stores (stride 1568B) caused
//   3.4x write amplification (WRITE_SIZE 536MB). Now: per-wave LDS transpose
//   (8KB, XOR-swizzled) -> coalesced 256B row stores.

typedef __attribute__((ext_vector_type(8)))  short short8;
typedef __attribute__((ext_vector_type(16))) float f32x16;

constexpr int Bn = 128, Units = 49, Cap = 8, OW = 28, HWp = 784;
constexpr int Nn = 392, Npad = 448;
constexpr int BM = 256, BNt = 64, NB = 7;      // grid: 392 mb x 7 nb = 2744 (%8==0)
constexpr int NSLOT = 82;                      // 81 taps + 1 zero slot
constexpr size_t XW_BYTES = (size_t)Bn * 64 * 64 * 16 * 2;     // 16,777,216
constexpr size_t BW_BYTES = (size_t)NSLOT * 2 * Npad * 8 * 2;  // 1,175,552

__device__ inline unsigned short f2bf(float f) {
    unsigned u = __float_as_uint(f);
    u += 0x7FFF + ((u >> 16) & 1);
    return (unsigned short)(u >> 16);
}

// ---- prep 1: x NCHW f32 -> NHWC bf16 (verified) -----------------------------
__global__ __launch_bounds__(256) void prep_x(const float* __restrict__ x,
                                              unsigned short* __restrict__ xw) {
    __shared__ unsigned short tile[64 * 16];   // [x][c]
    const int b = blockIdx.x >> 6, y = blockIdx.x & 63;
    const int t = threadIdx.x;
    const int c = t >> 4, x0 = (t & 15) * 4;
    const float4 v = *(const float4*)(x + (((size_t)b * 16 + c) * 64 + y) * 64 + x0);
    tile[(x0 + 0) * 16 + c] = f2bf(v.x);
    tile[(x0 + 1) * 16 + c] = f2bf(v.y);
    tile[(x0 + 2) * 16 + c] = f2bf(v.z);
    tile[(x0 + 3) * 16 + c] = f2bf(v.w);
    __syncthreads();
    const ushort4 o = *(const ushort4*)&tile[t * 4];
    *(ushort4*)(xw + (size_t)blockIdx.x * 1024 + t * 4) = o;
}

// ---- prep 2: W[392][16][9][9] -> bw[(p*2+h)*448 + n][8ch] bf16 (verified) ---
__global__ __launch_bounds__(256) void prep_w(const float* __restrict__ W,
                                              unsigned short* __restrict__ bw) {
    const int idx = blockIdx.x * 256 + threadIdx.x;
    if (idx >= NSLOT * 2 * Npad) return;
    const int n  = idx % Npad;
    const int ph = idx / Npad;
    const int h = ph & 1, p = ph >> 1;
    unsigned short vals[8];
    if (p < 81 && n < Nn) {
#pragma unroll
        for (int j = 0; j < 8; ++j)
            vals[j] = f2bf(W[(size_t)(n * 16 + h * 8 + j) * 81 + p]);
    } else {
#pragma unroll
        for (int j = 0; j < 8; ++j) vals[j] = 0;
    }
    *(ushort4*)(bw + (size_t)idx * 8)     = make_ushort4(vals[0], vals[1], vals[2], vals[3]);
    *(ushort4*)(bw + (size_t)idx * 8 + 4) = make_ushort4(vals[4], vals[5], vals[6], vals[7]);
}

// ---- main -------------------------------------------------------------------
#define MFMA32(A, B, C) __builtin_amdgcn_mfma_f32_32x32x16_bf16(A, B, C, 0, 0, 0)

__global__ __launch_bounds__(256, 3) void pcaps_mfma32(
    const unsigned short* __restrict__ xw,
    const unsigned short* __restrict__ bw,
    const float* __restrict__ bias,
    float* __restrict__ out)
{
    __shared__ int tbl[84];                    // tap byte offsets; 81..83 = 0
    __shared__ float xpose[4][32 * 64];        // per-wave 32m x 64n transpose tile
    const int t = threadIdx.x;
    if (t < 84) tbl[t] = (t < 81) ? (t / 9) * 2048 + (t % 9) * 32 : 0;

    // XCD swizzle: nwg = 2744 (%8==0); each XCD gets a contiguous 343-wgid chunk.
    const int cpx  = gridDim.x >> 3;
    const int wgid = (blockIdx.x & 7) * cpx + (blockIdx.x >> 3);
    const int nb = wgid % NB, mb = wgid / NB;
    const int n0 = nb * BNt;

    const int w = t >> 6, l = t & 63;
    const int r = l & 31, h = l >> 5;          // idx-in-frag, k-half

    int abase[2];                              // x (B-operand) m-frags
#pragma unroll
    for (int mi = 0; mi < 2; ++mi) {
        const int m = mb * BM + w * 64 + mi * 32 + r;
        const int b = m / HWp;
        const int hw = m - b * HWp;
        const int oy = hw / OW, ox = hw - oy * OW;
        abase[mi] = b * 131072 + oy * 4096 + ox * 64 + h * 16;   // bytes
    }
    const int bb0 = ((h * Npad) + n0 + r) * 16;   // slot-0 W byte offset; +14336/slot

    // acc[ni][mi]: D rows = n-frag ni, cols = m-frag mi  (D = W · X^T)
    f32x16 acc[2][2];
#pragma unroll
    for (int ni = 0; ni < 2; ++ni)
#pragma unroll
        for (int mi = 0; mi < 2; ++mi)
#pragma unroll
            for (int e = 0; e < 16; ++e) acc[ni][mi][e] = 0.f;

    __syncthreads();

    const char* __restrict__ xc = (const char*)xw;
    const char* __restrict__ bc = (const char*)bw;

    // prologue: slots 0,1
    int kA = tbl[0], kB = tbl[1];
    short8 aA0 = *(const short8*)(xc + (abase[0] + kA));
    short8 aA1 = *(const short8*)(xc + (abase[1] + kA));
    short8 bA0 = *(const short8*)(bc + bb0);
    short8 bA1 = *(const short8*)(bc + (bb0 + 512));
    short8 aB0 = *(const short8*)(xc + (abase[0] + kB));
    short8 aB1 = *(const short8*)(xc + (abase[1] + kB));
    short8 bB0 = *(const short8*)(bc + (bb0 + 14336));
    short8 bB1 = *(const short8*)(bc + (bb0 + 14336 + 512));
    int bbA = bb0 + 2 * 14336;
    int bbB = bb0 + 3 * 14336;

    for (int s = 0; s < 40; ++s) {             // MFMA slots 2s,2s+1; load 2s+2,2s+3
        const int k2 = tbl[2 * s + 2], k3 = tbl[2 * s + 3];

        acc[0][0] = MFMA32(bA0, aA0, acc[0][0]);
        acc[0][1] = MFMA32(bA0, aA1, acc[0][1]);
        acc[1][0] = MFMA32(bA1, aA0, acc[1][0]);
        acc[1][1] = MFMA32(bA1, aA1, acc[1][1]);
        aA0 = *(const short8*)(xc + (abase[0] + k2));
        aA1 = *(const short8*)(xc + (abase[1] + k2));
        bA0 = *(const short8*)(bc + bbA);
        bA1 = *(const short8*)(bc + (bbA + 512));
        bbA += 28672;

        acc[0][0] = MFMA32(bB0, aB0, acc[0][0]);
        acc[0][1] = MFMA32(bB0, aB1, acc[0][1]);
        acc[1][0] = MFMA32(bB1, aB0, acc[1][0]);
        acc[1][1] = MFMA32(bB1, aB1, acc[1][1]);
        aB0 = *(const short8*)(xc + (abase[0] + k3));
        aB1 = *(const short8*)(xc + (abase[1] + k3));
        bB0 = *(const short8*)(bc + bbB);
        bB1 = *(const short8*)(bc + (bbB + 512));
        bbB += 28672;
    }
    // tail: slots 80,81 (81 = zero slot)
    acc[0][0] = MFMA32(bA0, aA0, acc[0][0]);
    acc[0][1] = MFMA32(bA0, aA1, acc[0][1]);
    acc[1][0] = MFMA32(bA1, aA0, acc[1][0]);
    acc[1][1] = MFMA32(bA1, aA1, acc[1][1]);
    acc[0][0] = MFMA32(bB0, aB0, acc[0][0]);
    acc[0][1] = MFMA32(bB0, aB1, acc[0][1]);
    acc[1][0] = MFMA32(bB1, aB0, acc[1][0]);
    acc[1][1] = MFMA32(bB1, aB1, acc[1][1]);

    // epilogue: lane holds col m = (...)+r, n-rows (reg&3)+8*(reg>>2)+4h.
    // quad 4q..4q+3 = half a squash group; partner half at lane xor 32.
    // squash in regs -> per-wave LDS transpose (XOR-swizzled) -> coalesced stores.
    float* __restrict__ wl = xpose[w];
#pragma unroll
    for (int mi = 0; mi < 2; ++mi) {
#pragma unroll
        for (int ni = 0; ni < 2; ++ni) {
#pragma unroll
            for (int q = 0; q < 4; ++q) {
                const int nloc = ni * 32 + 8 * q + 4 * h;       // local n of quad base
                const int nqb  = n0 + nloc;
                const float4 bq = *(const float4*)(bias + ((nqb < Nn) ? nqb : 0));
                float e0 = acc[ni][mi][4 * q + 0] + bq.x;
                float e1 = acc[ni][mi][4 * q + 1] + bq.y;
                float e2 = acc[ni][mi][4 * q + 2] + bq.z;
                float e3 = acc[ni][mi][4 * q + 3] + bq.w;
                float msq = e0 * e0;
                msq = fmaf(e1, e1, msq);
                msq = fmaf(e2, e2, msq);
                msq = fmaf(e3, e3, msq);
                msq += __shfl_xor(msq, 32);     // partner half-group
                const float scale = sqrtf(msq) / (1.0f + msq);
                float4 o;
                o.x = e0 * scale; o.y = e1 * scale;
                o.z = e2 * scale; o.w = e3 * scale;
                const int col = nloc ^ ((r & 15) << 2);         // bank-spread, 16B-aligned
                *(float4*)(&wl[r * 64 + col]) = o;
            }
        }
        __syncthreads();
        // coalesced store: 16-lane groups cover one m-row's 64 n (256B)
        const int g  = l >> 4;          // 0..3 -> m-row offset
        const int c4 = (l & 15) * 4;    // n within row
        const int nn = n0 + c4;
        const bool ok = (nn < Nn);
#pragma unroll
        for (int j = 0; j < 8; ++j) {
            const int ml  = g + j * 4;                          // 0..31
            const int col = c4 ^ ((ml & 15) << 2);
            const float4 v = *(const float4*)(&wl[ml * 64 + col]);
            if (ok) {
                const int m = mb * BM + w * 64 + mi * 32 + ml;
                *reinterpret_cast<float4*>(out + (size_t)m * Nn + nn) = v;
            }
        }
        __syncthreads();
    }
}

// ---- fallback (round-1 direct conv, known-correct) --------------------------
__global__ __launch_bounds__(128) void pcaps_direct(
    const float* __restrict__ x, const float* __restrict__ W,
    const float* __restrict__ bias, float* __restrict__ out)
{
    const int blk = blockIdx.x;
    const int tile = blk % 7;
    const int u = (blk / 7) % Units;
    const int b = blk / (7 * Units);
    const int hw = tile * 128 + threadIdx.x;
    const bool active = (hw < HWp);
    const int oy = active ? (hw / OW) : 0;
    const int ox = active ? (hw % OW) : 0;
    const float* xb = x + (size_t)b * (16 * 64 * 64) + (size_t)(oy * 2) * 64 + ox * 2;
    const float* wu = W + (size_t)u * (Cap * 1296);
    float acc[Cap];
#pragma unroll
    for (int j = 0; j < Cap; ++j) acc[j] = bias[u * Cap + j];
    for (int c = 0; c < 16; ++c) {
        const float* xcp = xb + c * (64 * 64);
        const float* wc = wu + c * 81;
#pragma unroll
        for (int ky = 0; ky < 9; ++ky) {
            const float* xr = xcp + ky * 64;
            float xv[9];
#pragma unroll
            for (int kx = 0; kx < 9; ++kx) xv[kx] = xr[kx];
#pragma unroll
            for (int kx = 0; kx < 9; ++kx)
#pragma unroll
                for (int j = 0; j < Cap; ++j)
                    acc[j] = fmaf(xv[kx], wc[j * 1296 + ky * 9 + kx], acc[j]);
        }
    }
    if (active) {
        float msq = 0.f;
#pragma unroll
        for (int j = 0; j < Cap; ++j) msq = fmaf(acc[j], acc[j], msq);
        const float scale = sqrtf(msq) / (1.0f + msq);
        float* op = out + (size_t)b * (HWp * Nn) + (size_t)hw * Nn + u * Cap;
        float4 o0, o1;
        o0.x = acc[0] * scale; o0.y = acc[1] * scale; o0.z = acc[2] * scale; o0.w = acc[3] * scale;
        o1.x = acc[4] * scale; o1.y = acc[5] * scale; o1.z = acc[6] * scale; o1.w = acc[7] * scale;
        *reinterpret_cast<float4*>(op) = o0;
        *reinterpret_cast<float4*>(op + 4) = o1;
    }
}

extern "C" void kernel_launch(void* const* d_in, const int* in_sizes, int n_in,
                              void* d_out, int out_size, void* d_ws, size_t ws_size,
                              hipStream_t stream)
{
    const float* x  = (const float*)d_in[0];
    const float* W  = (const float*)d_in[1];
    const float* bs = (const float*)d_in[2];
    float* out      = (float*)d_out;

    if (ws_size < XW_BYTES + BW_BYTES) {
        pcaps_direct<<<Bn * Units * 7, 128, 0, stream>>>(x, W, bs, out);
        return;
    }

    unsigned short* xw = (unsigned short*)d_ws;
    unsigned short* bw = (unsigned short*)((char*)d_ws + XW_BYTES);

    prep_x<<<Bn * 64, 256, 0, stream>>>(x, xw);
    prep_w<<<(NSLOT * 2 * Npad + 255) / 256, 256, 0, stream>>>(W, bw);
    pcaps_mfma32<<<(100352 / BM) * NB, 256, 0, stream>>>(xw, bw, bs, out);
}

// Round 7
// 220.414 us; speedup vs baseline: 2.1304x; 2.1304x over previous
//
#include <hip/hip_runtime.h>

// PrimaryCaps implicit GEMM, round 7: r4 base (non-swapped MFMA, clean stores,
// WRITE_SIZE == output) + fully-unrolled K-loop (compile-time tap offsets, no
// LDS table, no barriers) + (256,3) occupancy + XCD swizzle.

typedef __attribute__((ext_vector_type(8)))  short short8;
typedef __attribute__((ext_vector_type(16))) float f32x16;

constexpr int Bn = 128, Units = 49, Cap = 8, OW = 28, HWp = 784;
constexpr int Nn = 392, Npad = 448;
constexpr int BM = 256, BNt = 64, NB = 7;      // grid: 392 mb x 7 nb = 2744 (%8==0)
constexpr int NSLOT = 82;                      // 81 taps + 1 zero slot
constexpr size_t XW_BYTES = (size_t)Bn * 64 * 64 * 16 * 2;     // 16,777,216
constexpr size_t BW_BYTES = (size_t)NSLOT * 2 * Npad * 8 * 2;  // 1,175,552

__device__ inline unsigned short f2bf(float f) {
    unsigned u = __float_as_uint(f);
    u += 0x7FFF + ((u >> 16) & 1);
    return (unsigned short)(u >> 16);
}

// ---- prep 1: x NCHW f32 -> NHWC bf16 (verified) -----------------------------
__global__ __launch_bounds__(256) void prep_x(const float* __restrict__ x,
                                              unsigned short* __restrict__ xw) {
    __shared__ unsigned short tile[64 * 16];   // [x][c]
    const int b = blockIdx.x >> 6, y = blockIdx.x & 63;
    const int t = threadIdx.x;
    const int c = t >> 4, x0 = (t & 15) * 4;
    const float4 v = *(const float4*)(x + (((size_t)b * 16 + c) * 64 + y) * 64 + x0);
    tile[(x0 + 0) * 16 + c] = f2bf(v.x);
    tile[(x0 + 1) * 16 + c] = f2bf(v.y);
    tile[(x0 + 2) * 16 + c] = f2bf(v.z);
    tile[(x0 + 3) * 16 + c] = f2bf(v.w);
    __syncthreads();
    const ushort4 o = *(const ushort4*)&tile[t * 4];
    *(ushort4*)(xw + (size_t)blockIdx.x * 1024 + t * 4) = o;
}

// ---- prep 2: W[392][16][9][9] -> bw[(p*2+h)*448 + n][8ch] bf16 (verified) ---
__global__ __launch_bounds__(256) void prep_w(const float* __restrict__ W,
                                              unsigned short* __restrict__ bw) {
    const int idx = blockIdx.x * 256 + threadIdx.x;
    if (idx >= NSLOT * 2 * Npad) return;
    const int n  = idx % Npad;
    const int ph = idx / Npad;
    const int h = ph & 1, p = ph >> 1;
    unsigned short vals[8];
    if (p < 81 && n < Nn) {
#pragma unroll
        for (int j = 0; j < 8; ++j)
            vals[j] = f2bf(W[(size_t)(n * 16 + h * 8 + j) * 81 + p]);
    } else {
#pragma unroll
        for (int j = 0; j < 8; ++j) vals[j] = 0;
    }
    *(ushort4*)(bw + (size_t)idx * 8)     = make_ushort4(vals[0], vals[1], vals[2], vals[3]);
    *(ushort4*)(bw + (size_t)idx * 8 + 4) = make_ushort4(vals[4], vals[5], vals[6], vals[7]);
}

// ---- main -------------------------------------------------------------------
#define MFMA32(A, B, C) __builtin_amdgcn_mfma_f32_32x32x16_bf16(A, B, C, 0, 0, 0)

__global__ __launch_bounds__(256, 3) void pcaps_mfma32(
    const unsigned short* __restrict__ xw,
    const unsigned short* __restrict__ bw,
    const float* __restrict__ bias,
    float* __restrict__ out)
{
    const int t = threadIdx.x;

    // XCD swizzle: nwg = 2744 (%8==0); each XCD gets a contiguous 343-wgid chunk.
    const int cpx  = gridDim.x >> 3;
    const int wgid = (blockIdx.x & 7) * cpx + (blockIdx.x >> 3);
    const int nb = wgid % NB, mb = wgid / NB;
    const int n0 = nb * BNt;

    const int w = t >> 6, l = t & 63;
    const int r = l & 31, h = l >> 5;          // idx-in-frag, k-half

    int abase[2];                              // x m-frag byte bases
#pragma unroll
    for (int mi = 0; mi < 2; ++mi) {
        const int m = mb * BM + w * 64 + mi * 32 + r;
        const int b = m / HWp;
        const int hw = m - b * HWp;
        const int oy = hw / OW, ox = hw - oy * OW;
        abase[mi] = b * 131072 + oy * 4096 + ox * 64 + h * 16;   // bytes
    }

    const char* __restrict__ a0 = (const char*)xw + abase[0];
    const char* __restrict__ a1 = (const char*)xw + abase[1];
    const char* __restrict__ bp = (const char*)bw + ((h * Npad) + n0 + r) * 16;

    f32x16 acc[2][2];
#pragma unroll
    for (int mi = 0; mi < 2; ++mi)
#pragma unroll
        for (int ni = 0; ni < 2; ++ni)
#pragma unroll
            for (int e = 0; e < 16; ++e) acc[mi][ni][e] = 0.f;

    short8 af[2][2], bf[2][2];                 // [slot parity][frag]
    // prologue: slots 0 (off 0) and 1 (off 32)
    af[0][0] = *(const short8*)(a0 + 0);
    af[0][1] = *(const short8*)(a1 + 0);
    bf[0][0] = *(const short8*)(bp + 0);
    bf[0][1] = *(const short8*)(bp + 512);
    af[1][0] = *(const short8*)(a0 + 32);
    af[1][1] = *(const short8*)(a1 + 32);
    bf[1][0] = *(const short8*)(bp + 14336);
    bf[1][1] = *(const short8*)(bp + 14336 + 512);

#pragma unroll
    for (int s = 0; s < NSLOT; ++s) {
        const int p = s & 1;
        acc[0][0] = MFMA32(af[p][0], bf[p][0], acc[0][0]);
        acc[0][1] = MFMA32(af[p][0], bf[p][1], acc[0][1]);
        acc[1][0] = MFMA32(af[p][1], bf[p][0], acc[1][0]);
        acc[1][1] = MFMA32(af[p][1], bf[p][1], acc[1][1]);
        if (s + 2 < NSLOT) {
            const int s2  = s + 2;
            const int off = (s2 / 9) * 2048 + (s2 % 9) * 32;   // compile-time tap offset
            af[p][0] = *(const short8*)(a0 + off);
            af[p][1] = *(const short8*)(a1 + off);
            bf[p][0] = *(const short8*)(bp + s2 * 14336);
            bf[p][1] = *(const short8*)(bp + s2 * 14336 + 512);
        }
    }

    // epilogue (r4-verified): bias + squash over 8 consecutive n (lanes r bits 0-2)
    float bv[2];
#pragma unroll
    for (int ni = 0; ni < 2; ++ni) {
        const int n = n0 + ni * 32 + r;
        bv[ni] = (n < Nn) ? bias[n] : 0.f;
    }
#pragma unroll
    for (int mi = 0; mi < 2; ++mi) {
#pragma unroll
        for (int ni = 0; ni < 2; ++ni) {
            const int n = n0 + ni * 32 + r;
            const bool nok = (n < Nn);
#pragma unroll
            for (int reg = 0; reg < 16; ++reg) {
                float e = acc[mi][ni][reg] + bv[ni];
                float sq = e * e;
                sq += __shfl_xor(sq, 1);
                sq += __shfl_xor(sq, 2);
                sq += __shfl_xor(sq, 4);
                const float scale = sqrtf(sq) / (1.0f + sq);
                if (nok) {
                    const int rowc = (reg & 3) + 8 * (reg >> 2) + 4 * h;
                    const int m = mb * BM + w * 64 + mi * 32 + rowc;
                    out[(size_t)m * Nn + n] = e * scale;
                }
            }
        }
    }
}

// ---- fallback (round-1 direct conv, known-correct) --------------------------
__global__ __launch_bounds__(128) void pcaps_direct(
    const float* __restrict__ x, const float* __restrict__ W,
    const float* __restrict__ bias, float* __restrict__ out)
{
    const int blk = blockIdx.x;
    const int tile = blk % 7;
    const int u = (blk / 7) % Units;
    const int b = blk / (7 * Units);
    const int hw = tile * 128 + threadIdx.x;
    const bool active = (hw < HWp);
    const int oy = active ? (hw / OW) : 0;
    const int ox = active ? (hw % OW) : 0;
    const float* xb = x + (size_t)b * (16 * 64 * 64) + (size_t)(oy * 2) * 64 + ox * 2;
    const float* wu = W + (size_t)u * (Cap * 1296);
    float acc[Cap];
#pragma unroll
    for (int j = 0; j < Cap; ++j) acc[j] = bias[u * Cap + j];
    for (int c = 0; c < 16; ++c) {
        const float* xcp = xb + c * (64 * 64);
        const float* wc = wu + c * 81;
#pragma unroll
        for (int ky = 0; ky < 9; ++ky) {
            const float* xr = xcp + ky * 64;
            float xv[9];
#pragma unroll
            for (int kx = 0; kx < 9; ++kx) xv[kx] = xr[kx];
#pragma unroll
            for (int kx = 0; kx < 9; ++kx)
#pragma unroll
                for (int j = 0; j < Cap; ++j)
                    acc[j] = fmaf(xv[kx], wc[j * 1296 + ky * 9 + kx], acc[j]);
        }
    }
    if (active) {
        float msq = 0.f;
#pragma unroll
        for (int j = 0; j < Cap; ++j) msq = fmaf(acc[j], acc[j], msq);
        const float scale = sqrtf(msq) / (1.0f + msq);
        float* op = out + (size_t)b * (HWp * Nn) + (size_t)hw * Nn + u * Cap;
        float4 o0, o1;
        o0.x = acc[0] * scale; o0.y = acc[1] * scale; o0.z = acc[2] * scale; o0.w = acc[3] * scale;
        o1.x = acc[4] * scale; o1.y = acc[5] * scale; o1.z = acc[6] * scale; o1.w = acc[7] * scale;
        *reinterpret_cast<float4*>(op) = o0;
        *reinterpret_cast<float4*>(op + 4) = o1;
    }
}

extern "C" void kernel_launch(void* const* d_in, const int* in_sizes, int n_in,
                              void* d_out, int out_size, void* d_ws, size_t ws_size,
                              hipStream_t stream)
{
    const float* x  = (const float*)d_in[0];
    const float* W  = (const float*)d_in[1];
    const float* bs = (const float*)d_in[2];
    float* out      = (float*)d_out;

    if (ws_size < XW_BYTES + BW_BYTES) {
        pcaps_direct<<<Bn * Units * 7, 128, 0, stream>>>(x, W, bs, out);
        return;
    }

    unsigned short* xw = (unsigned short*)d_ws;
    unsigned short* bw = (unsigned short*)((char*)d_ws + XW_BYTES);

    prep_x<<<Bn * 64, 256, 0, stream>>>(x, xw);
    prep_w<<<(NSLOT * 2 * Npad + 255) / 256, 256, 0, stream>>>(W, bw);
    pcaps_mfma32<<<(100352 / BM) * NB, 256, 0, stream>>>(xw, bw, bs, out);
}

// Round 8
// 220.300 us; speedup vs baseline: 2.1315x; 1.0005x over previous
//
#include <hip/hip_runtime.h>

// PrimaryCaps implicit GEMM, round 8: r7 (unrolled K, clean stores, (256,3),
// XCD swizzle) with prefetch depth 2 -> 4. r7 was latency-bound (MfmaUtil 21%,
// VALUBusy 23%, HBM 11%): 2-slot prefetch ~192cyc cover < ~200cyc L2 latency.
// Depth 4 = ~384cyc cover. Reg math: 64 frag VGPR + ~28 addr + 64 AGPR = ~156 < 170.

typedef __attribute__((ext_vector_type(8)))  short short8;
typedef __attribute__((ext_vector_type(16))) float f32x16;

constexpr int Bn = 128, Units = 49, Cap = 8, OW = 28, HWp = 784;
constexpr int Nn = 392, Npad = 448;
constexpr int BM = 256, BNt = 64, NB = 7;      // grid: 392 mb x 7 nb = 2744 (%8==0)
constexpr int NSLOT = 82;                      // 81 taps + 1 zero slot
constexpr size_t XW_BYTES = (size_t)Bn * 64 * 64 * 16 * 2;     // 16,777,216
constexpr size_t BW_BYTES = (size_t)NSLOT * 2 * Npad * 8 * 2;  // 1,175,552

__device__ inline unsigned short f2bf(float f) {
    unsigned u = __float_as_uint(f);
    u += 0x7FFF + ((u >> 16) & 1);
    return (unsigned short)(u >> 16);
}

// ---- prep 1: x NCHW f32 -> NHWC bf16 (verified) -----------------------------
__global__ __launch_bounds__(256) void prep_x(const float* __restrict__ x,
                                              unsigned short* __restrict__ xw) {
    __shared__ unsigned short tile[64 * 16];   // [x][c]
    const int b = blockIdx.x >> 6, y = blockIdx.x & 63;
    const int t = threadIdx.x;
    const int c = t >> 4, x0 = (t & 15) * 4;
    const float4 v = *(const float4*)(x + (((size_t)b * 16 + c) * 64 + y) * 64 + x0);
    tile[(x0 + 0) * 16 + c] = f2bf(v.x);
    tile[(x0 + 1) * 16 + c] = f2bf(v.y);
    tile[(x0 + 2) * 16 + c] = f2bf(v.z);
    tile[(x0 + 3) * 16 + c] = f2bf(v.w);
    __syncthreads();
    const ushort4 o = *(const ushort4*)&tile[t * 4];
    *(ushort4*)(xw + (size_t)blockIdx.x * 1024 + t * 4) = o;
}

// ---- prep 2: W[392][16][9][9] -> bw[(p*2+h)*448 + n][8ch] bf16 (verified) ---
__global__ __launch_bounds__(256) void prep_w(const float* __restrict__ W,
                                              unsigned short* __restrict__ bw) {
    const int idx = blockIdx.x * 256 + threadIdx.x;
    if (idx >= NSLOT * 2 * Npad) return;
    const int n  = idx % Npad;
    const int ph = idx / Npad;
    const int h = ph & 1, p = ph >> 1;
    unsigned short vals[8];
    if (p < 81 && n < Nn) {
#pragma unroll
        for (int j = 0; j < 8; ++j)
            vals[j] = f2bf(W[(size_t)(n * 16 + h * 8 + j) * 81 + p]);
    } else {
#pragma unroll
        for (int j = 0; j < 8; ++j) vals[j] = 0;
    }
    *(ushort4*)(bw + (size_t)idx * 8)     = make_ushort4(vals[0], vals[1], vals[2], vals[3]);
    *(ushort4*)(bw + (size_t)idx * 8 + 4) = make_ushort4(vals[4], vals[5], vals[6], vals[7]);
}

// ---- main -------------------------------------------------------------------
#define MFMA32(A, B, C) __builtin_amdgcn_mfma_f32_32x32x16_bf16(A, B, C, 0, 0, 0)

__global__ __launch_bounds__(256, 3) void pcaps_mfma32(
    const unsigned short* __restrict__ xw,
    const unsigned short* __restrict__ bw,
    const float* __restrict__ bias,
    float* __restrict__ out)
{
    const int t = threadIdx.x;

    // XCD swizzle: nwg = 2744 (%8==0); each XCD gets a contiguous 343-wgid chunk.
    const int cpx  = gridDim.x >> 3;
    const int wgid = (blockIdx.x & 7) * cpx + (blockIdx.x >> 3);
    const int nb = wgid % NB, mb = wgid / NB;
    const int n0 = nb * BNt;

    const int w = t >> 6, l = t & 63;
    const int r = l & 31, h = l >> 5;          // idx-in-frag, k-half

    int abase[2];                              // x m-frag byte bases
#pragma unroll
    for (int mi = 0; mi < 2; ++mi) {
        const int m = mb * BM + w * 64 + mi * 32 + r;
        const int b = m / HWp;
        const int hw = m - b * HWp;
        const int oy = hw / OW, ox = hw - oy * OW;
        abase[mi] = b * 131072 + oy * 4096 + ox * 64 + h * 16;   // bytes
    }

    const char* __restrict__ a0 = (const char*)xw + abase[0];
    const char* __restrict__ a1 = (const char*)xw + abase[1];
    const char* __restrict__ bp = (const char*)bw + ((h * Npad) + n0 + r) * 16;

    f32x16 acc[2][2];
#pragma unroll
    for (int mi = 0; mi < 2; ++mi)
#pragma unroll
        for (int ni = 0; ni < 2; ++ni)
#pragma unroll
            for (int e = 0; e < 16; ++e) acc[mi][ni][e] = 0.f;

    short8 af[4][2], bf[4][2];                 // 4-deep pipeline [slot mod 4][frag]
#pragma unroll
    for (int s = 0; s < 4; ++s) {              // prologue: slots 0..3
        const int off = (s / 9) * 2048 + (s % 9) * 32;
        af[s][0] = *(const short8*)(a0 + off);
        af[s][1] = *(const short8*)(a1 + off);
        bf[s][0] = *(const short8*)(bp + s * 14336);
        bf[s][1] = *(const short8*)(bp + s * 14336 + 512);
    }

#pragma unroll
    for (int s = 0; s < NSLOT; ++s) {
        const int p = s & 3;
        acc[0][0] = MFMA32(af[p][0], bf[p][0], acc[0][0]);
        acc[0][1] = MFMA32(af[p][0], bf[p][1], acc[0][1]);
        acc[1][0] = MFMA32(af[p][1], bf[p][0], acc[1][0]);
        acc[1][1] = MFMA32(af[p][1], bf[p][1], acc[1][1]);
        if (s + 4 < NSLOT) {
            const int s2  = s + 4;
            const int off = (s2 / 9) * 2048 + (s2 % 9) * 32;   // compile-time tap offset
            af[p][0] = *(const short8*)(a0 + off);
            af[p][1] = *(const short8*)(a1 + off);
            bf[p][0] = *(const short8*)(bp + s2 * 14336);
            bf[p][1] = *(const short8*)(bp + s2 * 14336 + 512);
        }
    }

    // epilogue (r4-verified): bias + squash over 8 consecutive n (lanes r bits 0-2)
    float bv[2];
#pragma unroll
    for (int ni = 0; ni < 2; ++ni) {
        const int n = n0 + ni * 32 + r;
        bv[ni] = (n < Nn) ? bias[n] : 0.f;
    }
#pragma unroll
    for (int mi = 0; mi < 2; ++mi) {
#pragma unroll
        for (int ni = 0; ni < 2; ++ni) {
            const int n = n0 + ni * 32 + r;
            const bool nok = (n < Nn);
#pragma unroll
            for (int reg = 0; reg < 16; ++reg) {
                float e = acc[mi][ni][reg] + bv[ni];
                float sq = e * e;
                sq += __shfl_xor(sq, 1);
                sq += __shfl_xor(sq, 2);
                sq += __shfl_xor(sq, 4);
                const float scale = sqrtf(sq) / (1.0f + sq);
                if (nok) {
                    const int rowc = (reg & 3) + 8 * (reg >> 2) + 4 * h;
                    const int m = mb * BM + w * 64 + mi * 32 + rowc;
                    out[(size_t)m * Nn + n] = e * scale;
                }
            }
        }
    }
}

// ---- fallback (round-1 direct conv, known-correct) --------------------------
__global__ __launch_bounds__(128) void pcaps_direct(
    const float* __restrict__ x, const float* __restrict__ W,
    const float* __restrict__ bias, float* __restrict__ out)
{
    const int blk = blockIdx.x;
    const int tile = blk % 7;
    const int u = (blk / 7) % Units;
    const int b = blk / (7 * Units);
    const int hw = tile * 128 + threadIdx.x;
    const bool active = (hw < HWp);
    const int oy = active ? (hw / OW) : 0;
    const int ox = active ? (hw % OW) : 0;
    const float* xb = x + (size_t)b * (16 * 64 * 64) + (size_t)(oy * 2) * 64 + ox * 2;
    const float* wu = W + (size_t)u * (Cap * 1296);
    float acc[Cap];
#pragma unroll
    for (int j = 0; j < Cap; ++j) acc[j] = bias[u * Cap + j];
    for (int c = 0; c < 16; ++c) {
        const float* xcp = xb + c * (64 * 64);
        const float* wc = wu + c * 81;
#pragma unroll
        for (int ky = 0; ky < 9; ++ky) {
            const float* xr = xcp + ky * 64;
            float xv[9];
#pragma unroll
            for (int kx = 0; kx < 9; ++kx) xv[kx] = xr[kx];
#pragma unroll
            for (int kx = 0; kx < 9; ++kx)
#pragma unroll
                for (int j = 0; j < Cap; ++j)
                    acc[j] = fmaf(xv[kx], wc[j * 1296 + ky * 9 + kx], acc[j]);
        }
    }
    if (active) {
        float msq = 0.f;
#pragma unroll
        for (int j = 0; j < Cap; ++j) msq = fmaf(acc[j], acc[j], msq);
        const float scale = sqrtf(msq) / (1.0f + msq);
        float* op = out + (size_t)b * (HWp * Nn) + (size_t)hw * Nn + u * Cap;
        float4 o0, o1;
        o0.x = acc[0] * scale; o0.y = acc[1] * scale; o0.z = acc[2] * scale; o0.w = acc[3] * scale;
        o1.x = acc[4] * scale; o1.y = acc[5] * scale; o1.z = acc[6] * scale; o1.w = acc[7] * scale;
        *reinterpret_cast<float4*>(op) = o0;
        *reinterpret_cast<float4*>(op + 4) = o1;
    }
}

extern "C" void kernel_launch(void* const* d_in, const int* in_sizes, int n_in,
                              void* d_out, int out_size, void* d_ws, size_t ws_size,
                              hipStream_t stream)
{
    const float* x  = (const float*)d_in[0];
    const float* W  = (const float*)d_in[1];
    const float* bs = (const float*)d_in[2];
    float* out      = (float*)d_out;

    if (ws_size < XW_BYTES + BW_BYTES) {
        pcaps_direct<<<Bn * Units * 7, 128, 0, stream>>>(x, W, bs, out);
        return;
    }

    unsigned short* xw = (unsigned short*)d_ws;
    unsigned short* bw = (unsigned short*)((char*)d_ws + XW_BYTES);

    prep_x<<<Bn * 64, 256, 0, stream>>>(x, xw);
    prep_w<<<(NSLOT * 2 * Npad + 255) / 256, 256, 0, stream>>>(W, bw);
    pcaps_mfma32<<<(100352 / BM) * NB, 256, 0, stream>>>(xw, bw, bs, out);
}